// Round 13
// baseline (253.333 us; speedup 1.0000x reference)
//
#include <hip/hip_runtime.h>

// CRF log-partition forward, MI355X. 64 blocks (1 per sequence) x 64 threads
// (ONE wave -> ZERO barriers; in-wave DS ordering makes the single LDS p
// buffer safe). Rounds 6/9/10 plateaued at ~660 cyc/step with ~480 cyc of
// fixed cross-wave cost (s_barrier + ds latency + drain); this removes it.
//
// Lane l owns tags {2l, 2l+1}. E = exp(T) held as f16 pairs in 128 named
// h2 registers (EA_m = (E[2m][2l],E[2m+1][2l]), EB_m same for col 2l+1).
// State p stored in LDS as packed f16 pairs (64 dwords). Per step:
// 16x ds_read_b128 broadcast -> 128 v_dot2_f32_f16 (8 chains) -> emission
// exp2 -> renormalize by exponent of the FRESH p0 (readfirstlane, lane 0
// owns tag 0; keeps stored p0 in [1,2), f16 range safe) -> cvt_pkrtz ->
// ds_write_b32. No barrier anywhere; emission prefetch distance 4.
//
//   q'_j = exp(e_j) * (sum_i q_i E_ij) * 2^(-eS),  eS = exponent(q'_0)
//   o   += eS (integer, exact);  alpha_j = ln2 * (o + log2 q_j)
// f16 E/p rounding: ~5e-4 relative, absmax ~0.2-2 vs threshold 54.

#define LOG2E 1.4426950408889634f
#define LN2   0.6931471805599453f

typedef float    f2 __attribute__((ext_vector_type(2)));
typedef _Float16 h2 __attribute__((ext_vector_type(2)));

// cvt_pkrtz returns __fp16x2; bit_cast to our h2 (_Float16x2), same 32 bits
#define PKRTZ(a, b) __builtin_bit_cast(h2, __builtin_amdgcn_cvt_pkrtz((a), (b)))

__global__ __launch_bounds__(64)
__attribute__((amdgpu_waves_per_eu(1, 1)))
void crf_forward(
    const float* __restrict__ emissions,   // [64, 512, 128]
    const float* __restrict__ transitions, // [128, 128]
    const float* __restrict__ start_t,     // [128]
    const float* __restrict__ end_t,       // [128]
    const int*   __restrict__ lengths,     // [64]
    float* __restrict__ out)               // [64]
{
    constexpr int N = 128;
    constexpr int L = 512;
    const int b = blockIdx.x;
    const int l = threadIdx.x;          // lane, owns tags 2l and 2l+1

    __shared__ alignas(16) float pbuf[64];   // packed f16 pairs (p_2w, p_2w+1)

    // ---- one-time: E tile as 128 NAMED h2 registers (128 VGPRs)
    h2 EA_0,  EA_1,  EA_2,  EA_3,  EA_4,  EA_5,  EA_6,  EA_7;
    h2 EA_8,  EA_9,  EA_10, EA_11, EA_12, EA_13, EA_14, EA_15;
    h2 EA_16, EA_17, EA_18, EA_19, EA_20, EA_21, EA_22, EA_23;
    h2 EA_24, EA_25, EA_26, EA_27, EA_28, EA_29, EA_30, EA_31;
    h2 EA_32, EA_33, EA_34, EA_35, EA_36, EA_37, EA_38, EA_39;
    h2 EA_40, EA_41, EA_42, EA_43, EA_44, EA_45, EA_46, EA_47;
    h2 EA_48, EA_49, EA_50, EA_51, EA_52, EA_53, EA_54, EA_55;
    h2 EA_56, EA_57, EA_58, EA_59, EA_60, EA_61, EA_62, EA_63;
    h2 EB_0,  EB_1,  EB_2,  EB_3,  EB_4,  EB_5,  EB_6,  EB_7;
    h2 EB_8,  EB_9,  EB_10, EB_11, EB_12, EB_13, EB_14, EB_15;
    h2 EB_16, EB_17, EB_18, EB_19, EB_20, EB_21, EB_22, EB_23;
    h2 EB_24, EB_25, EB_26, EB_27, EB_28, EB_29, EB_30, EB_31;
    h2 EB_32, EB_33, EB_34, EB_35, EB_36, EB_37, EB_38, EB_39;
    h2 EB_40, EB_41, EB_42, EB_43, EB_44, EB_45, EB_46, EB_47;
    h2 EB_48, EB_49, EB_50, EB_51, EB_52, EB_53, EB_54, EB_55;
    h2 EB_56, EB_57, EB_58, EB_59, EB_60, EB_61, EB_62, EB_63;
    {
#define INIT_M(m)                                                              \
        {                                                                      \
            f2 r0 = *reinterpret_cast<const f2*>(                              \
                transitions + (size_t)(2 * (m)) * N + 2 * l);                  \
            f2 r1 = *reinterpret_cast<const f2*>(                              \
                transitions + (size_t)(2 * (m) + 1) * N + 2 * l);              \
            EA_##m = PKRTZ(__builtin_amdgcn_exp2f(r0.x * LOG2E),               \
                           __builtin_amdgcn_exp2f(r1.x * LOG2E));              \
            EB_##m = PKRTZ(__builtin_amdgcn_exp2f(r0.y * LOG2E),               \
                           __builtin_amdgcn_exp2f(r1.y * LOG2E));              \
        }
        INIT_M(0)  INIT_M(1)  INIT_M(2)  INIT_M(3)
        INIT_M(4)  INIT_M(5)  INIT_M(6)  INIT_M(7)
        INIT_M(8)  INIT_M(9)  INIT_M(10) INIT_M(11)
        INIT_M(12) INIT_M(13) INIT_M(14) INIT_M(15)
        INIT_M(16) INIT_M(17) INIT_M(18) INIT_M(19)
        INIT_M(20) INIT_M(21) INIT_M(22) INIT_M(23)
        INIT_M(24) INIT_M(25) INIT_M(26) INIT_M(27)
        INIT_M(28) INIT_M(29) INIT_M(30) INIT_M(31)
        INIT_M(32) INIT_M(33) INIT_M(34) INIT_M(35)
        INIT_M(36) INIT_M(37) INIT_M(38) INIT_M(39)
        INIT_M(40) INIT_M(41) INIT_M(42) INIT_M(43)
        INIT_M(44) INIT_M(45) INIT_M(46) INIT_M(47)
        INIT_M(48) INIT_M(49) INIT_M(50) INIT_M(51)
        INIT_M(52) INIT_M(53) INIT_M(54) INIT_M(55)
        INIT_M(56) INIT_M(57) INIT_M(58) INIT_M(59)
        INIT_M(60) INIT_M(61) INIT_M(62) INIT_M(63)
#undef INIT_M
    }

    const int len = lengths[b];
    const float* eb = emissions + (size_t)b * L * N;

    // ---- init: p = exp(start + e0), normalized by fresh p0's exponent
    int o = 0;
    float qA, qB;
    {
        f2 st = *reinterpret_cast<const f2*>(start_t + 2 * l);
        f2 e0 = *reinterpret_cast<const f2*>(eb + 2 * l);
        float pA = __builtin_amdgcn_exp2f((st.x + e0.x) * LOG2E);
        float pB = __builtin_amdgcn_exp2f((st.y + e0.y) * LOG2E);
        int u0 = __builtin_amdgcn_readfirstlane(__float_as_int(pA));
        int eS = (int)(((unsigned)u0 >> 23) & 0xFFu) - 127;
        o += eS;
        float sc = __uint_as_float((unsigned)(127 - eS) << 23);
        qA = pA * sc; qB = pB * sc;
        pbuf[l] = __builtin_bit_cast(float, PKRTZ(qA, qB));
    }

    auto clampt = [&](int tt) { return tt < len ? tt : len - 1; };
    auto ldE = [&](int tt) {
        return *reinterpret_cast<const f2*>(eb + (size_t)tt * N + 2 * l);
    };

    auto STEP = [&](f2 ecur) {
        // broadcast-read all 128 f16 p's (16x ds_read_b128, same addr/lane)
        const float4* pv = reinterpret_cast<const float4*>(pbuf);
        float4 Q0 = pv[0],  Q1 = pv[1],  Q2 = pv[2],  Q3 = pv[3];
        float4 Q4 = pv[4],  Q5 = pv[5],  Q6 = pv[6],  Q7 = pv[7];
        float4 Q8 = pv[8],  Q9 = pv[9],  Q10 = pv[10], Q11 = pv[11];
        float4 Q12 = pv[12], Q13 = pv[13], Q14 = pv[14], Q15 = pv[15];

        float esA = __builtin_amdgcn_exp2f(ecur.x * LOG2E);
        float esB = __builtin_amdgcn_exp2f(ecur.y * LOG2E);

        // 128 v_dot2_f32_f16, 8 accumulator chains (depth 16)
        float a0 = 0.f, a1 = 0.f, a2 = 0.f, a3 = 0.f;
        float b0 = 0.f, b1 = 0.f, b2 = 0.f, b3 = 0.f;
#define D(m, Q, C, ch)                                                         \
        {                                                                      \
            h2 pm = __builtin_bit_cast(h2, Q.C);                               \
            a##ch = __builtin_amdgcn_fdot2(pm, EA_##m, a##ch, false);          \
            b##ch = __builtin_amdgcn_fdot2(pm, EB_##m, b##ch, false);          \
        }
        D(0,  Q0,  x, 0) D(1,  Q0,  y, 1) D(2,  Q0,  z, 2) D(3,  Q0,  w, 3)
        D(4,  Q1,  x, 0) D(5,  Q1,  y, 1) D(6,  Q1,  z, 2) D(7,  Q1,  w, 3)
        D(8,  Q2,  x, 0) D(9,  Q2,  y, 1) D(10, Q2,  z, 2) D(11, Q2,  w, 3)
        D(12, Q3,  x, 0) D(13, Q3,  y, 1) D(14, Q3,  z, 2) D(15, Q3,  w, 3)
        D(16, Q4,  x, 0) D(17, Q4,  y, 1) D(18, Q4,  z, 2) D(19, Q4,  w, 3)
        D(20, Q5,  x, 0) D(21, Q5,  y, 1) D(22, Q5,  z, 2) D(23, Q5,  w, 3)
        D(24, Q6,  x, 0) D(25, Q6,  y, 1) D(26, Q6,  z, 2) D(27, Q6,  w, 3)
        D(28, Q7,  x, 0) D(29, Q7,  y, 1) D(30, Q7,  z, 2) D(31, Q7,  w, 3)
        D(32, Q8,  x, 0) D(33, Q8,  y, 1) D(34, Q8,  z, 2) D(35, Q8,  w, 3)
        D(36, Q9,  x, 0) D(37, Q9,  y, 1) D(38, Q9,  z, 2) D(39, Q9,  w, 3)
        D(40, Q10, x, 0) D(41, Q10, y, 1) D(42, Q10, z, 2) D(43, Q10, w, 3)
        D(44, Q11, x, 0) D(45, Q11, y, 1) D(46, Q11, z, 2) D(47, Q11, w, 3)
        D(48, Q12, x, 0) D(49, Q12, y, 1) D(50, Q12, z, 2) D(51, Q12, w, 3)
        D(52, Q13, x, 0) D(53, Q13, y, 1) D(54, Q13, z, 2) D(55, Q13, w, 3)
        D(56, Q14, x, 0) D(57, Q14, y, 1) D(58, Q14, z, 2) D(59, Q14, w, 3)
        D(60, Q15, x, 0) D(61, Q15, y, 1) D(62, Q15, z, 2) D(63, Q15, w, 3)
#undef D
        float dA = (a0 + a1) + (a2 + a3);
        float dB = (b0 + b1) + (b2 + b3);

        float pA = esA * dA;
        float pB = esB * dB;

        // renormalize by the FRESH p0's exponent (lane 0, tag 0): stored
        // p0 stays in [1,2); spread <= ~2^13 -- safe in f16.
        int u0 = __builtin_amdgcn_readfirstlane(__float_as_int(pA));
        int eS = (int)(((unsigned)u0 >> 23) & 0xFFu) - 127;
        o += eS;
        float sc = __uint_as_float((unsigned)(127 - eS) << 23);
        qA = pA * sc; qB = pB * sc;
        pbuf[l] = __builtin_bit_cast(float, PKRTZ(qA, qB));
        // no barrier: in-wave DS ordering covers write->next-step-read
    };

    // ---- main loop: distance-4 emission prefetch, manual 4-way unroll
    f2 ra = ldE(clampt(1));
    f2 rb = ldE(clampt(2));
    f2 rc = ldE(clampt(3));
    f2 rd = ldE(clampt(4));

    int t = 1;
    while (t < len) {
        STEP(ra); ra = ldE(clampt(t + 4)); ++t; if (t >= len) break;
        STEP(rb); rb = ldE(clampt(t + 4)); ++t; if (t >= len) break;
        STEP(rc); rc = ldE(clampt(t + 4)); ++t; if (t >= len) break;
        STEP(rd); rd = ldE(clampt(t + 4)); ++t;
    }

    // ---- finalize: out[b] = ln2 * (o + log2(sum_j q_j * exp(end_j)))
    {
        f2 ef = *reinterpret_cast<const f2*>(end_t + 2 * l);
        float vend = qA * __builtin_amdgcn_exp2f(ef.x * LOG2E)
                   + qB * __builtin_amdgcn_exp2f(ef.y * LOG2E);
        #pragma unroll
        for (int m = 1; m < 64; m <<= 1) vend += __shfl_xor(vend, m);
        if (l == 0)
            out[b] = LN2 * ((float)o + __builtin_amdgcn_logf(vend));
    }
}

extern "C" void kernel_launch(void* const* d_in, const int* in_sizes, int n_in,
                              void* d_out, int out_size, void* d_ws, size_t ws_size,
                              hipStream_t stream) {
    const float* emissions   = (const float*)d_in[0];
    const float* transitions = (const float*)d_in[1];
    const float* start_t     = (const float*)d_in[2];
    const float* end_t       = (const float*)d_in[3];
    const int*   lengths     = (const int*)d_in[4];
    float* out = (float*)d_out;

    crf_forward<<<dim3(64), dim3(64), 0, stream>>>(
        emissions, transitions, start_t, end_t, lengths, out);
}

// Round 14
// 187.533 us; speedup vs baseline: 1.3509x; 1.3509x over previous
//
#include <hip/hip_runtime.h>

// CRF log-partition forward, MI355X. 64 blocks (1 per sequence) x 256 threads
// (4 waves, pinned 1 wave/EU). Hybrid of R10 (4-wave quad-only combine) and
// R13 (f16 state + v_dot2_f32_f16):
//  - p stored in LDS as packed f16 pairs -> lane reads its 32-i chunk as
//    4x ds_read_b128 (16 wave-instr/step block-wide, half of R10)
//  - 32 fdot2 per lane (i-chunk 32 x j-pair {2g,2g+1}), 4 chains
//  - E tile only 32 h2 = 32 VGPRs: no AGPR parking (R13 lesson: big E tiles
//    get parked in AGPRs, VGPR_Count 132 cap, accvgpr shuttles on the chain)
//  - quad-only DPP combine (xor1+xor2), writer k==0 stores packed pair b32
//  - renormalizer: f16 exponent of OLD q0 (broadcast b32), folded into the
//    exp2 argument: q' = exp2(e*log2e - eS) * dot;  o += eS (exact)
//  - lgkmcnt-only barrier (R6 lesson: __syncthreads drains vmcnt and kills
//    the emission prefetch); distance-4 prefetch ring
// f16 q/E rounding validated: R13 ran f16 state end-to-end, absmax 0.0.
// Layout: pair-dword for tags {2g,2g+1} at (g>>4)*20 + (g&15); chunk k base
// k*20 dwords -> the 4 broadcast b128 addresses hit disjoint bank quads.

#define LOG2E 1.4426950408889634f
#define LN2   0.6931471805599453f

// LDS-only workgroup barrier: no vmcnt drain (cross-wave data is LDS only).
#define LDS_BARRIER() asm volatile("s_waitcnt lgkmcnt(0)\n\ts_barrier" ::: "memory")

typedef float    f2 __attribute__((ext_vector_type(2)));
typedef _Float16 h2 __attribute__((ext_vector_type(2)));

// cvt_pkrtz returns __fp16x2; bit_cast to h2 (_Float16x2), same 32 bits
#define PKRTZ(a, b) __builtin_bit_cast(h2, __builtin_amdgcn_cvt_pkrtz((a), (b)))

template <int CTRL>
__device__ __forceinline__ float dpp_f(float x) {
    return __int_as_float(
        __builtin_amdgcn_mov_dpp(__float_as_int(x), CTRL, 0xF, 0xF, false));
}
// quad_perm codes: xor1 = 0xB1, xor2 = 0x4E

__global__ __launch_bounds__(256)
__attribute__((amdgpu_waves_per_eu(1, 1)))
void crf_forward(
    const float* __restrict__ emissions,   // [64, 512, 128]
    const float* __restrict__ transitions, // [128, 128]
    const float* __restrict__ start_t,     // [128]
    const float* __restrict__ end_t,       // [128]
    const int*   __restrict__ lengths,     // [64]
    float* __restrict__ out)               // [64]
{
    constexpr int N = 128;
    constexpr int L = 512;
    const int b   = blockIdx.x;
    const int tid = threadIdx.x;
    const int g   = tid >> 2;   // tag pair {2g, 2g+1}, g in [0,64)
    const int k   = tid & 3;    // i-chunk: tags [32k, 32k+32) = pair-dwords [16k,16k+16)

    // f16-pair dwords; chunk k at padded base 20k (16B-aligned, disjoint banks)
    __shared__ alignas(16) float pbuf[2][80];
    __shared__ float wsum[4];

    // ---- one-time: E tile as 32 NAMED h2 registers (32 VGPRs).
    // EA_m = (E[32k+2m][2g], E[32k+2m+1][2g]); EB_m same for col 2g+1.
    h2 EA_0,  EA_1,  EA_2,  EA_3,  EA_4,  EA_5,  EA_6,  EA_7;
    h2 EA_8,  EA_9,  EA_10, EA_11, EA_12, EA_13, EA_14, EA_15;
    h2 EB_0,  EB_1,  EB_2,  EB_3,  EB_4,  EB_5,  EB_6,  EB_7;
    h2 EB_8,  EB_9,  EB_10, EB_11, EB_12, EB_13, EB_14, EB_15;
    {
        const float* tb = transitions + (size_t)(32 * k) * N + 2 * g;
#define INIT_M(m)                                                              \
        {                                                                      \
            f2 r0 = *reinterpret_cast<const f2*>(tb + (size_t)(2 * (m)) * N);  \
            f2 r1 = *reinterpret_cast<const f2*>(tb + (size_t)(2 * (m) + 1) * N); \
            EA_##m = PKRTZ(__builtin_amdgcn_exp2f(r0.x * LOG2E),               \
                           __builtin_amdgcn_exp2f(r1.x * LOG2E));              \
            EB_##m = PKRTZ(__builtin_amdgcn_exp2f(r0.y * LOG2E),               \
                           __builtin_amdgcn_exp2f(r1.y * LOG2E));              \
        }
        INIT_M(0)  INIT_M(1)  INIT_M(2)  INIT_M(3)
        INIT_M(4)  INIT_M(5)  INIT_M(6)  INIT_M(7)
        INIT_M(8)  INIT_M(9)  INIT_M(10) INIT_M(11)
        INIT_M(12) INIT_M(13) INIT_M(14) INIT_M(15)
#undef INIT_M
    }

    const int len = lengths[b];
    const float* eb = emissions + (size_t)b * L * N;

    // ---- init: raw q = exp(start + e0) for the lane's pair; k==0 writes
    int o = 0;
    int cur = 0;
    float qA, qB;
    {
        f2 st = *reinterpret_cast<const f2*>(start_t + 2 * g);
        f2 e0 = *reinterpret_cast<const f2*>(eb + 2 * g);
        qA = __builtin_amdgcn_exp2f((st.x + e0.x) * LOG2E);
        qB = __builtin_amdgcn_exp2f((st.y + e0.y) * LOG2E);
        if (k == 0)
            pbuf[0][(g >> 4) * 20 + (g & 15)] =
                __builtin_bit_cast(float, PKRTZ(qA, qB));
    }
    LDS_BARRIER();

    auto clampt = [&](int tt) { return tt < len ? tt : len - 1; };
    auto ldE = [&](int tt) {
        return *reinterpret_cast<const f2*>(eb + (size_t)tt * N + 2 * g);
    };

    auto STEP = [&](f2 ecur) {
        // old q0 (broadcast b32) + my 16 pair-dwords (4x b128, disjoint banks)
        float q0w = pbuf[cur][0];
        const float4* pv = reinterpret_cast<const float4*>(&pbuf[cur][k * 20]);
        float4 Q0 = pv[0], Q1 = pv[1], Q2 = pv[2], Q3 = pv[3];

        // eS = f16 exponent of old q0 (tag 0 = low half), bias 15
        unsigned u0 = __float_as_uint(q0w);
        int eS = (int)((u0 >> 10) & 0x1Fu) - 15;
        o += eS;
        float feS = (float)eS;
        float esA = __builtin_amdgcn_exp2f(ecur.x * LOG2E - feS);
        float esB = __builtin_amdgcn_exp2f(ecur.y * LOG2E - feS);

        // 32 v_dot2_f32_f16 over the 32i x 2j tile, 4 chains (depth 8)
        float aA0 = 0.f, aA1 = 0.f, aB0 = 0.f, aB1 = 0.f;
#define D0(m, Qc)                                                              \
        {                                                                      \
            h2 pm = __builtin_bit_cast(h2, Qc);                                \
            aA0 = __builtin_amdgcn_fdot2(pm, EA_##m, aA0, false);              \
            aB0 = __builtin_amdgcn_fdot2(pm, EB_##m, aB0, false);              \
        }
#define D1(m, Qc)                                                              \
        {                                                                      \
            h2 pm = __builtin_bit_cast(h2, Qc);                                \
            aA1 = __builtin_amdgcn_fdot2(pm, EA_##m, aA1, false);              \
            aB1 = __builtin_amdgcn_fdot2(pm, EB_##m, aB1, false);              \
        }
        D0(0,  Q0.x) D1(1,  Q0.y) D0(2,  Q0.z) D1(3,  Q0.w)
        D0(4,  Q1.x) D1(5,  Q1.y) D0(6,  Q1.z) D1(7,  Q1.w)
        D0(8,  Q2.x) D1(9,  Q2.y) D0(10, Q2.z) D1(11, Q2.w)
        D0(12, Q3.x) D1(13, Q3.y) D0(14, Q3.z) D1(15, Q3.w)
#undef D0
#undef D1
        float dA = aA0 + aA1;
        float dB = aB0 + aB1;

        // quad butterfly (DPP only): all 4 quad lanes get the full i-sum
        dA += dpp_f<0xB1>(dA); dB += dpp_f<0xB1>(dB);
        dA += dpp_f<0x4E>(dA); dB += dpp_f<0x4E>(dB);

        qA = esA * dA;
        qB = esB * dB;
        cur ^= 1;
        if (k == 0)
            pbuf[cur][(g >> 4) * 20 + (g & 15)] =
                __builtin_bit_cast(float, PKRTZ(qA, qB));
        LDS_BARRIER();
    };

    // ---- main loop: distance-4 emission prefetch, manual 4-way unroll
    f2 ra = ldE(clampt(1));
    f2 rb = ldE(clampt(2));
    f2 rc = ldE(clampt(3));
    f2 rd = ldE(clampt(4));

    int t = 1;
    while (t < len) {
        STEP(ra); ra = ldE(clampt(t + 4)); ++t; if (t >= len) break;
        STEP(rb); rb = ldE(clampt(t + 4)); ++t; if (t >= len) break;
        STEP(rc); rc = ldE(clampt(t + 4)); ++t; if (t >= len) break;
        STEP(rd); rd = ldE(clampt(t + 4)); ++t;
    }

    // ---- finalize: each quad holds its pair's q redundantly (x4) -> 0.25
    {
        f2 ef = *reinterpret_cast<const f2*>(end_t + 2 * g);
        float vend = qA * __builtin_amdgcn_exp2f(ef.x * LOG2E)
                   + qB * __builtin_amdgcn_exp2f(ef.y * LOG2E);
        vend *= 0.25f;
        #pragma unroll
        for (int m = 1; m < 64; m <<= 1) vend += __shfl_xor(vend, m);
        if ((tid & 63) == 0) wsum[tid >> 6] = vend;
    }
    LDS_BARRIER();
    if (tid == 0)
        out[b] = LN2 * ((float)o + __builtin_amdgcn_logf(
                     (wsum[0] + wsum[1]) + (wsum[2] + wsum[3])));
}

extern "C" void kernel_launch(void* const* d_in, const int* in_sizes, int n_in,
                              void* d_out, int out_size, void* d_ws, size_t ws_size,
                              hipStream_t stream) {
    const float* emissions   = (const float*)d_in[0];
    const float* transitions = (const float*)d_in[1];
    const float* start_t     = (const float*)d_in[2];
    const float* end_t       = (const float*)d_in[3];
    const int*   lengths     = (const int*)d_in[4];
    float* out = (float*)d_out;

    crf_forward<<<dim3(64), dim3(256), 0, stream>>>(
        emissions, transitions, start_t, end_t, lengths, out);
}